// Round 8
// baseline (91.610 us; speedup 1.0000x reference)
//
#include <hip/hip_runtime.h>
#include <math.h>

// Problem constants
#define NBATCH   32768
#define OWN_DIM  7
#define INTR_DIM 5
#define N_HEADS  3
#define HEAD_DIM 5
#define N_INTR   256
#define ROWLEN   1287   // OWN_DIM + N_INTR*INTR_DIM
#define XDIM     22     // OWN_DIM + N_HEADS*HEAD_DIM
#define H1DIM    256
#define H2DIM    256

typedef __attribute__((ext_vector_type(8))) short bf16x8;
typedef __attribute__((ext_vector_type(4))) float f32x4;

__device__ __forceinline__ float leaky02(float x) {
    return fmaxf(x, 0.2f * x);
}

__device__ __forceinline__ unsigned short f2bf_rne(float f) {
    unsigned u = __float_as_uint(f);
    return (unsigned short)((u + 0x7FFFu + ((u >> 16) & 1u)) >> 16);
}

// ---------------- Kernel A: attention + layernorm -> x (B x 22) ----------------
// FOUR samples per wave (16 lanes each), 16 samples per 256-thread block.
// r7 analysis: VALU floor ~29 us, measured ~74 us -> stall-bound. The (256,2)
// bound let the allocator run to 256 VGPR = 2 waves/SIMD; s_load waits (75 Wk
// floats don't fit in SGPRs with h-inner) + vmem latency were exposed.
// This round: (256,4) -> <=128 VGPR -> 4 resident waves/SIMD for latency hiding.
__global__ __launch_bounds__(256, 4) void attn_ln_kernel(
    const float* __restrict__ obs,
    const float* __restrict__ Wq, const float* __restrict__ bq,
    const float* __restrict__ Wk, const float* __restrict__ bk,
    const float* __restrict__ Wv, const float* __restrict__ bv,
    const float* __restrict__ v_att, const float* __restrict__ temp,
    const float* __restrict__ ln_g, const float* __restrict__ ln_b,
    float* __restrict__ xout)
{
    const int wid  = threadIdx.x >> 6;
    const int lane = threadIdx.x & 63;
    const int grp  = lane >> 4;     // sample slot within wave (0..3)
    const int gl   = lane & 15;     // lane within 16-lane sample group
    const int s    = blockIdx.x * 16 + wid * 4 + grp;
    const float* row = obs + (size_t)s * ROWLEN;

    const float fac = fabsf(temp[0]) * 0.4472135954999579f;      // |T|/sqrt(5)
    const float facl2e = fac * 1.4426950408889634f;              // * log2e
    const float TL2E = 2.885390081777927f;                       // 2*log2e

    // own[0..6] of this lane's sample (16-way broadcast per group)
    float own[OWN_DIM];
    #pragma unroll
    for (int o = 0; o < OWN_DIM; ++o) own[o] = row[o];

    // per-head score constants: va2 = -2*facl2e*v_att, vasum = facl2e*sum(v_att)
    float va2[N_HEADS][HEAD_DIM], vasum[N_HEADS];
    #pragma unroll
    for (int h = 0; h < N_HEADS; ++h) {
        float ssum = 0.0f;
        #pragma unroll
        for (int d = 0; d < HEAD_DIM; ++d) {
            float v = v_att[h*HEAD_DIM + d];
            ssum += v;
            va2[h][d] = v * (-2.0f * facl2e);
        }
        vasum[h] = ssum * facl2e;
    }

    // qb[h][d] = q + bk for this lane's sample
    float qb[N_HEADS][HEAD_DIM];
    #pragma unroll
    for (int h = 0; h < N_HEADS; ++h)
        #pragma unroll
        for (int d = 0; d < HEAD_DIM; ++d) {
            float a = bq[h*HEAD_DIM + d] + bk[h*HEAD_DIM + d];
            #pragma unroll
            for (int o = 0; o < OWN_DIM; ++o)
                a = fmaf(own[o], Wq[h*OWN_DIM*HEAD_DIM + o*HEAD_DIM + d], a);
            qb[h][d] = a;
        }

    // accumulators: svp[h][i] = sum_n e_n*xi_n[i], es[h] = sum_n e_n
    float svp[N_HEADS][INTR_DIM] = {};
    float es[N_HEADS] = {};

    // 16 items per lane: n = gl + 16*r (group reads 320B contiguous per r)
    #pragma unroll
    for (int r = 0; r < 16; ++r) {
        const float* it = row + OWN_DIM + (gl + 16*r) * INTR_DIM;
        float xi[INTR_DIM];
        #pragma unroll
        for (int i = 0; i < INTR_DIM; ++i) xi[i] = it[i];
        float asum = fabsf(xi[0]) + fabsf(xi[1]) + fabsf(xi[2])
                   + fabsf(xi[3]) + fabsf(xi[4]);
        const float npf = (asum < 1e-6f) ? 0.0f : 1.0f;
        #pragma unroll
        for (int h = 0; h < N_HEADS; ++h) {
            float dot = vasum[h];
            #pragma unroll
            for (int d = 0; d < HEAD_DIM; ++d) {
                float t = qb[h][d];
                #pragma unroll
                for (int i = 0; i < INTR_DIM; ++i)
                    t = fmaf(xi[i], Wk[h*INTR_DIM*HEAD_DIM + i*HEAD_DIM + d], t);
                float e = __builtin_amdgcn_exp2f(t * TL2E);
                float rc = __builtin_amdgcn_rcpf(e + 1.0f);
                dot = fmaf(va2[h][d], rc, dot);     // == facl2e*sum va*tanh
            }
            float e = npf * __builtin_amdgcn_exp2f(dot);
            es[h] += e;
            #pragma unroll
            for (int i = 0; i < INTR_DIM; ++i)
                svp[h][i] = fmaf(e, xi[i], svp[h][i]);
        }
    }

    // 4-level butterfly within each 16-lane group (18 values)
    #pragma unroll
    for (int o = 1; o < 16; o <<= 1) {
        #pragma unroll
        for (int h = 0; h < N_HEADS; ++h) {
            es[h] += __shfl_xor(es[h], o, 64);
            #pragma unroll
            for (int i = 0; i < INTR_DIM; ++i)
                svp[h][i] += __shfl_xor(svp[h][i], o, 64);
        }
    }

    // normalize + deferred V projection: ctx = (svp/es) @ Wv + bv*live
    float ctx[N_HEADS][HEAD_DIM];
    #pragma unroll
    for (int h = 0; h < N_HEADS; ++h) {
        const float live = (es[h] > 0.0f) ? 1.0f : 0.0f;
        const float rinv = live * __builtin_amdgcn_rcpf(es[h]);
        float svn[INTR_DIM];
        #pragma unroll
        for (int i = 0; i < INTR_DIM; ++i) svn[i] = svp[h][i] * rinv;
        #pragma unroll
        for (int d = 0; d < HEAD_DIM; ++d) {
            float c = bv[h*HEAD_DIM + d] * live;
            #pragma unroll
            for (int i = 0; i < INTR_DIM; ++i)
                c = fmaf(svn[i], Wv[h*INTR_DIM*HEAD_DIM + i*HEAD_DIM + d], c);
            ctx[h][d] = c;
        }
    }

    // layernorm over x = [own(7), ctx(15)] (redundant across the 16 group lanes)
    float sum = 0.0f;
    #pragma unroll
    for (int o = 0; o < OWN_DIM; ++o) sum += own[o];
    #pragma unroll
    for (int h = 0; h < N_HEADS; ++h)
        #pragma unroll
        for (int d = 0; d < HEAD_DIM; ++d) sum += ctx[h][d];
    const float mu = sum * (1.0f / 22.0f);
    float var = 0.0f;
    #pragma unroll
    for (int o = 0; o < OWN_DIM; ++o) { float dd = own[o] - mu; var += dd*dd; }
    #pragma unroll
    for (int h = 0; h < N_HEADS; ++h)
        #pragma unroll
        for (int d = 0; d < HEAD_DIM; ++d) { float dd = ctx[h][d] - mu; var += dd*dd; }
    var *= (1.0f / 22.0f);
    const float rs = rsqrtf(var + 1e-5f);

    // lane gl writes elements gl and gl+16 (if <22) via static select chains
    float xv0 = own[0];
    #pragma unroll
    for (int o = 1; o < OWN_DIM; ++o) xv0 = (gl == o) ? own[o] : xv0;
    #pragma unroll
    for (int j = 0; j < 15; ++j) xv0 = (gl == OWN_DIM + j) ? ctx[j/5][j%5] : xv0;
    float xv1 = ctx[1][4];                    // element 16 -> ctx j=9
    #pragma unroll
    for (int j = 10; j < 15; ++j) xv1 = (gl == j - 9) ? ctx[j/5][j%5] : xv1;

    float* xo = xout + (size_t)s * XDIM;
    xo[gl] = (xv0 - mu) * rs * ln_g[gl] + ln_b[gl];
    if (gl < XDIM - 16) {
        xo[16 + gl] = (xv1 - mu) * rs * ln_g[16 + gl] + ln_b[16 + gl];
    }
}

// ---------------- Kernel B: MLP 22->256->256->2 (+log_std) ----------------
// (unchanged — 4.4 us, MFMA layer-2, verified round 5)
__global__ __launch_bounds__(256) void mlp_kernel(
    const float* __restrict__ x,
    const float* __restrict__ W1, const float* __restrict__ b1,
    const float* __restrict__ W2, const float* __restrict__ b2,
    const float* __restrict__ Wf, const float* __restrict__ bf,
    const float* __restrict__ lstd, float* __restrict__ out)
{
    __shared__ __align__(16) float xs[32 * XDIM];              //  2.8 KB
    __shared__ __align__(16) unsigned char h1b[32 * 256 * 2];  // 16 KB bf16 [m][k]
    __shared__ __align__(16) unsigned char w2b[256 * 64 * 2];  // 32 KB bf16 [n][kchunk]
    __shared__ __align__(16) float wfs[H2DIM * 2];             //  2 KB
    __shared__ float oacc[4][32][2];                           //  1 KB

    const int t   = threadIdx.x;
    const int blk = blockIdx.x;

    for (int i = t; i < 32 * XDIM; i += 256) xs[i] = x[(size_t)blk * 32 * XDIM + i];
    for (int i = t; i < H2DIM * 2; i += 256) wfs[i] = Wf[i];

    // ---- layer 1: thread t computes h1[:, t] -> bf16 LDS column ----
    float w1r[XDIM];
    #pragma unroll
    for (int i = 0; i < XDIM; ++i) w1r[i] = W1[i * H1DIM + t];
    const float b1t = b1[t];
    __syncthreads();
    for (int e = 0; e < 32; ++e) {
        float a = b1t;
        #pragma unroll
        for (int i = 0; i < XDIM; ++i) a += xs[e * XDIM + i] * w1r[i];
        a = leaky02(a);
        int byte = e * 512 + t * 2;
        byte ^= ((e & 7) << 4);
        *(unsigned short*)(h1b + byte) = f2bf_rne(a);
    }

    // ---- layer 2: C[32][256] = h1 @ W2 via MFMA; wave owns 64-col slab ----
    const int wv_  = t >> 6;
    const int lane = t & 63;
    const int mrow = lane & 15;
    const int qk   = lane >> 4;

    f32x4 acc[2][4];
    #pragma unroll
    for (int mt = 0; mt < 2; ++mt)
        #pragma unroll
        for (int nt = 0; nt < 4; ++nt)
            acc[mt][nt] = (f32x4){0.f, 0.f, 0.f, 0.f};

    for (int kc = 0; kc < 4; ++kc) {
        __syncthreads();
        {
            const int n = t;
            #pragma unroll
            for (int k8 = 0; k8 < 64; k8 += 8) {
                bf16x8 v;
                #pragma unroll
                for (int j = 0; j < 8; ++j) {
                    float w = W2[(size_t)(kc * 64 + k8 + j) * H2DIM + n];
                    v[j] = (short)f2bf_rne(w);
                }
                int byte = n * 128 + k8 * 2;
                byte ^= ((n & 7) << 4);
                *(bf16x8*)(w2b + byte) = v;
            }
        }
        __syncthreads();
        #pragma unroll
        for (int ks = 0; ks < 2; ++ks) {
            const int klocal = ks * 32;
            const int kglob  = kc * 64 + klocal;
            bf16x8 afrag[2], bfrag[4];
            #pragma unroll
            for (int mt = 0; mt < 2; ++mt) {
                const int rowi = mt * 16 + mrow;
                int byte = rowi * 512 + (kglob + 8 * qk) * 2;
                byte ^= ((rowi & 7) << 4);
                afrag[mt] = *(const bf16x8*)(h1b + byte);
            }
            #pragma unroll
            for (int nt = 0; nt < 4; ++nt) {
                const int col = wv_ * 64 + nt * 16 + mrow;
                int byte = col * 128 + (klocal + 8 * qk) * 2;
                byte ^= ((col & 7) << 4);
                bfrag[nt] = *(const bf16x8*)(w2b + byte);
            }
            #pragma unroll
            for (int mt = 0; mt < 2; ++mt)
                #pragma unroll
                for (int nt = 0; nt < 4; ++nt)
                    acc[mt][nt] = __builtin_amdgcn_mfma_f32_16x16x32_bf16(
                        afrag[mt], bfrag[nt], acc[mt][nt], 0, 0, 0);
        }
    }

    // ---- epilogue: +b2, leaky, layer-3 partials, reduce ----
    float b2n[4];
    #pragma unroll
    for (int nt = 0; nt < 4; ++nt) b2n[nt] = b2[wv_ * 64 + nt * 16 + mrow];

    float p[8][2];
    #pragma unroll
    for (int i = 0; i < 8; ++i) { p[i][0] = 0.f; p[i][1] = 0.f; }
    #pragma unroll
    for (int mt = 0; mt < 2; ++mt)
        #pragma unroll
        for (int nt = 0; nt < 4; ++nt) {
            const int n = wv_ * 64 + nt * 16 + mrow;
            #pragma unroll
            for (int reg = 0; reg < 4; ++reg) {
                float h2v = leaky02(acc[mt][nt][reg] + b2n[nt]);
                p[mt*4 + reg][0] = fmaf(h2v, wfs[2*n + 0], p[mt*4 + reg][0]);
                p[mt*4 + reg][1] = fmaf(h2v, wfs[2*n + 1], p[mt*4 + reg][1]);
            }
        }
    #pragma unroll
    for (int o = 1; o < 16; o <<= 1) {
        #pragma unroll
        for (int i = 0; i < 8; ++i) {
            p[i][0] += __shfl_xor(p[i][0], o, 64);
            p[i][1] += __shfl_xor(p[i][1], o, 64);
        }
    }
    if (mrow == 0) {
        #pragma unroll
        for (int mt = 0; mt < 2; ++mt)
            #pragma unroll
            for (int reg = 0; reg < 4; ++reg) {
                const int sample = mt * 16 + qk * 4 + reg;   // C row mapping (m89)
                oacc[wv_][sample][0] = p[mt*4 + reg][0];
                oacc[wv_][sample][1] = p[mt*4 + reg][1];
            }
    }
    __syncthreads();
    if (t < 32) {
        float o0 = bf[0], o1 = bf[1];
        #pragma unroll
        for (int w = 0; w < 4; ++w) { o0 += oacc[w][t][0]; o1 += oacc[w][t][1]; }
        float4 o4;
        o4.x = o0; o4.y = o1; o4.z = lstd[0]; o4.w = lstd[1];
        *(float4*)&out[(size_t)(blk * 32 + t) * 4] = o4;
    }
}

extern "C" void kernel_launch(void* const* d_in, const int* in_sizes, int n_in,
                              void* d_out, int out_size, void* d_ws, size_t ws_size,
                              hipStream_t stream) {
    const float* obs   = (const float*)d_in[0];
    const float* Wq    = (const float*)d_in[1];
    const float* bq    = (const float*)d_in[2];
    const float* Wk    = (const float*)d_in[3];
    const float* bk    = (const float*)d_in[4];
    const float* Wv    = (const float*)d_in[5];
    const float* bv    = (const float*)d_in[6];
    const float* v_att = (const float*)d_in[7];
    const float* temp  = (const float*)d_in[8];
    const float* ln_g  = (const float*)d_in[9];
    const float* ln_b  = (const float*)d_in[10];
    const float* W1    = (const float*)d_in[11];
    const float* b1    = (const float*)d_in[12];
    const float* W2    = (const float*)d_in[13];
    const float* b2    = (const float*)d_in[14];
    const float* Wf    = (const float*)d_in[15];
    const float* bf    = (const float*)d_in[16];
    const float* lstd  = (const float*)d_in[17];

    float* xbuf = (float*)d_ws;   // B x 22 normalized features (2.88 MB)
    float* outf = (float*)d_out;

    attn_ln_kernel<<<NBATCH / 16, 256, 0, stream>>>(
        obs, Wq, bq, Wk, bk, Wv, bv, v_att, temp, ln_g, ln_b, xbuf);
    mlp_kernel<<<NBATCH / 32, 256, 0, stream>>>(
        xbuf, W1, b1, W2, b2, Wf, bf, lstd, outf);
}

// Round 9
// 91.038 us; speedup vs baseline: 1.0063x; 1.0063x over previous
//
#include <hip/hip_runtime.h>
#include <math.h>

// Problem constants
#define NBATCH   32768
#define OWN_DIM  7
#define INTR_DIM 5
#define N_HEADS  3
#define HEAD_DIM 5
#define N_INTR   256
#define ROWLEN   1287   // OWN_DIM + N_INTR*INTR_DIM
#define XDIM     22     // OWN_DIM + N_HEADS*HEAD_DIM
#define H1DIM    256
#define H2DIM    256

typedef __attribute__((ext_vector_type(8))) short bf16x8;
typedef __attribute__((ext_vector_type(4))) float f32x4;

__device__ __forceinline__ float leaky02(float x) {
    return fmaxf(x, 0.2f * x);
}

__device__ __forceinline__ unsigned short f2bf_rne(float f) {
    unsigned u = __float_as_uint(f);
    return (unsigned short)((u + 0x7FFFu + ((u >> 16) & 1u)) >> 16);
}

// ---------------- Kernel A: attention + layernorm -> x (B x 22) ----------------
// FOUR samples per wave (16 lanes each), 16 samples/block, 16 items/lane.
// r8 analysis: natural xi working set (80 VGPR) blows the 128-VGPR/4-wave
// budget -> compiler either drops to 2 waves/SIMD or reloads late; ~56 us of
// memory stall either way (half the xi reads are HBM misses, ~900 cyc).
// Fix: explicit distance-2 software pipeline -> only 15 xi regs live; loads
// for item r+2 issue before compute of item r (~480 issue-cyc cover).
__global__ __launch_bounds__(256, 4) void attn_ln_kernel(
    const float* __restrict__ obs,
    const float* __restrict__ Wq, const float* __restrict__ bq,
    const float* __restrict__ Wk, const float* __restrict__ bk,
    const float* __restrict__ Wv, const float* __restrict__ bv,
    const float* __restrict__ v_att, const float* __restrict__ temp,
    const float* __restrict__ ln_g, const float* __restrict__ ln_b,
    float* __restrict__ xout)
{
    const int wid  = threadIdx.x >> 6;
    const int lane = threadIdx.x & 63;
    const int grp  = lane >> 4;     // sample slot within wave (0..3)
    const int gl   = lane & 15;     // lane within 16-lane sample group
    const int s    = blockIdx.x * 16 + wid * 4 + grp;
    const float* row = obs + (size_t)s * ROWLEN;

    const float fac = fabsf(temp[0]) * 0.4472135954999579f;      // |T|/sqrt(5)
    const float facl2e = fac * 1.4426950408889634f;              // * log2e
    const float TL2E = 2.885390081777927f;                       // 2*log2e

    // own[0..6] of this lane's sample (16-way broadcast per group)
    float own[OWN_DIM];
    #pragma unroll
    for (int o = 0; o < OWN_DIM; ++o) own[o] = row[o];

    // per-head score constants: va2 = -2*facl2e*v_att, vasum = facl2e*sum(v_att)
    float va2[N_HEADS][HEAD_DIM], vasum[N_HEADS];
    #pragma unroll
    for (int h = 0; h < N_HEADS; ++h) {
        float ssum = 0.0f;
        #pragma unroll
        for (int d = 0; d < HEAD_DIM; ++d) {
            float v = v_att[h*HEAD_DIM + d];
            ssum += v;
            va2[h][d] = v * (-2.0f * facl2e);
        }
        vasum[h] = ssum * facl2e;
    }

    // qb[h][d] = q + bk for this lane's sample
    float qb[N_HEADS][HEAD_DIM];
    #pragma unroll
    for (int h = 0; h < N_HEADS; ++h)
        #pragma unroll
        for (int d = 0; d < HEAD_DIM; ++d) {
            float a = bq[h*HEAD_DIM + d] + bk[h*HEAD_DIM + d];
            #pragma unroll
            for (int o = 0; o < OWN_DIM; ++o)
                a = fmaf(own[o], Wq[h*OWN_DIM*HEAD_DIM + o*HEAD_DIM + d], a);
            qb[h][d] = a;
        }

    // accumulators: svp[h][i] = sum_n e_n*xi_n[i], es[h] = sum_n e_n
    float svp[N_HEADS][INTR_DIM] = {};
    float es[N_HEADS] = {};

    // distance-2 pipelined item loop: items n = gl + 16*r, r = 0..15
    const float* base = row + OWN_DIM + gl * INTR_DIM;  // this lane's item r=0
    float xa[INTR_DIM], xb[INTR_DIM];
    #pragma unroll
    for (int i = 0; i < INTR_DIM; ++i) xa[i] = base[i];           // item r=0
    #pragma unroll
    for (int i = 0; i < INTR_DIM; ++i) xb[i] = base[80 + i];      // item r=1

    #pragma unroll
    for (int r = 0; r < 16; ++r) {
        // prefetch item r+2 (dead after r=13)
        float xn[INTR_DIM];
        if (r + 2 < 16) {
            #pragma unroll
            for (int i = 0; i < INTR_DIM; ++i) xn[i] = base[(r + 2) * 80 + i];
        } else {
            #pragma unroll
            for (int i = 0; i < INTR_DIM; ++i) xn[i] = 0.0f;
        }

        // compute on xa
        float asum = fabsf(xa[0]) + fabsf(xa[1]) + fabsf(xa[2])
                   + fabsf(xa[3]) + fabsf(xa[4]);
        const float npf = (asum < 1e-6f) ? 0.0f : 1.0f;
        #pragma unroll
        for (int h = 0; h < N_HEADS; ++h) {
            float dot = vasum[h];
            #pragma unroll
            for (int d = 0; d < HEAD_DIM; ++d) {
                float t = qb[h][d];
                #pragma unroll
                for (int i = 0; i < INTR_DIM; ++i)
                    t = fmaf(xa[i], Wk[h*INTR_DIM*HEAD_DIM + i*HEAD_DIM + d], t);
                float e = __builtin_amdgcn_exp2f(t * TL2E);
                float rc = __builtin_amdgcn_rcpf(e + 1.0f);
                dot = fmaf(va2[h][d], rc, dot);     // == facl2e*sum va*tanh
            }
            float e = npf * __builtin_amdgcn_exp2f(dot);
            es[h] += e;
            #pragma unroll
            for (int i = 0; i < INTR_DIM; ++i)
                svp[h][i] = fmaf(e, xa[i], svp[h][i]);
        }

        // rotate buffers (register renaming after full unroll)
        #pragma unroll
        for (int i = 0; i < INTR_DIM; ++i) { xa[i] = xb[i]; xb[i] = xn[i]; }
    }

    // 4-level butterfly within each 16-lane group (18 values)
    #pragma unroll
    for (int o = 1; o < 16; o <<= 1) {
        #pragma unroll
        for (int h = 0; h < N_HEADS; ++h) {
            es[h] += __shfl_xor(es[h], o, 64);
            #pragma unroll
            for (int i = 0; i < INTR_DIM; ++i)
                svp[h][i] += __shfl_xor(svp[h][i], o, 64);
        }
    }

    // normalize + deferred V projection: ctx = (svp/es) @ Wv + bv*live
    float ctx[N_HEADS][HEAD_DIM];
    #pragma unroll
    for (int h = 0; h < N_HEADS; ++h) {
        const float live = (es[h] > 0.0f) ? 1.0f : 0.0f;
        const float rinv = live * __builtin_amdgcn_rcpf(es[h]);
        float svn[INTR_DIM];
        #pragma unroll
        for (int i = 0; i < INTR_DIM; ++i) svn[i] = svp[h][i] * rinv;
        #pragma unroll
        for (int d = 0; d < HEAD_DIM; ++d) {
            float c = bv[h*HEAD_DIM + d] * live;
            #pragma unroll
            for (int i = 0; i < INTR_DIM; ++i)
                c = fmaf(svn[i], Wv[h*INTR_DIM*HEAD_DIM + i*HEAD_DIM + d], c);
            ctx[h][d] = c;
        }
    }

    // layernorm over x = [own(7), ctx(15)] (redundant across the 16 group lanes)
    float sum = 0.0f;
    #pragma unroll
    for (int o = 0; o < OWN_DIM; ++o) sum += own[o];
    #pragma unroll
    for (int h = 0; h < N_HEADS; ++h)
        #pragma unroll
        for (int d = 0; d < HEAD_DIM; ++d) sum += ctx[h][d];
    const float mu = sum * (1.0f / 22.0f);
    float var = 0.0f;
    #pragma unroll
    for (int o = 0; o < OWN_DIM; ++o) { float dd = own[o] - mu; var += dd*dd; }
    #pragma unroll
    for (int h = 0; h < N_HEADS; ++h)
        #pragma unroll
        for (int d = 0; d < HEAD_DIM; ++d) { float dd = ctx[h][d] - mu; var += dd*dd; }
    var *= (1.0f / 22.0f);
    const float rs = rsqrtf(var + 1e-5f);

    // lane gl writes elements gl and gl+16 (if <22) via static select chains
    float xv0 = own[0];
    #pragma unroll
    for (int o = 1; o < OWN_DIM; ++o) xv0 = (gl == o) ? own[o] : xv0;
    #pragma unroll
    for (int j = 0; j < 15; ++j) xv0 = (gl == OWN_DIM + j) ? ctx[j/5][j%5] : xv0;
    float xv1 = ctx[1][4];                    // element 16 -> ctx j=9
    #pragma unroll
    for (int j = 10; j < 15; ++j) xv1 = (gl == j - 9) ? ctx[j/5][j%5] : xv1;

    float* xo = xout + (size_t)s * XDIM;
    xo[gl] = (xv0 - mu) * rs * ln_g[gl] + ln_b[gl];
    if (gl < XDIM - 16) {
        xo[16 + gl] = (xv1 - mu) * rs * ln_g[16 + gl] + ln_b[16 + gl];
    }
}

// ---------------- Kernel B: MLP 22->256->256->2 (+log_std) ----------------
// (unchanged — 4.4 us, MFMA layer-2, verified round 5)
__global__ __launch_bounds__(256) void mlp_kernel(
    const float* __restrict__ x,
    const float* __restrict__ W1, const float* __restrict__ b1,
    const float* __restrict__ W2, const float* __restrict__ b2,
    const float* __restrict__ Wf, const float* __restrict__ bf,
    const float* __restrict__ lstd, float* __restrict__ out)
{
    __shared__ __align__(16) float xs[32 * XDIM];              //  2.8 KB
    __shared__ __align__(16) unsigned char h1b[32 * 256 * 2];  // 16 KB bf16 [m][k]
    __shared__ __align__(16) unsigned char w2b[256 * 64 * 2];  // 32 KB bf16 [n][kchunk]
    __shared__ __align__(16) float wfs[H2DIM * 2];             //  2 KB
    __shared__ float oacc[4][32][2];                           //  1 KB

    const int t   = threadIdx.x;
    const int blk = blockIdx.x;

    for (int i = t; i < 32 * XDIM; i += 256) xs[i] = x[(size_t)blk * 32 * XDIM + i];
    for (int i = t; i < H2DIM * 2; i += 256) wfs[i] = Wf[i];

    // ---- layer 1: thread t computes h1[:, t] -> bf16 LDS column ----
    float w1r[XDIM];
    #pragma unroll
    for (int i = 0; i < XDIM; ++i) w1r[i] = W1[i * H1DIM + t];
    const float b1t = b1[t];
    __syncthreads();
    for (int e = 0; e < 32; ++e) {
        float a = b1t;
        #pragma unroll
        for (int i = 0; i < XDIM; ++i) a += xs[e * XDIM + i] * w1r[i];
        a = leaky02(a);
        int byte = e * 512 + t * 2;
        byte ^= ((e & 7) << 4);
        *(unsigned short*)(h1b + byte) = f2bf_rne(a);
    }

    // ---- layer 2: C[32][256] = h1 @ W2 via MFMA; wave owns 64-col slab ----
    const int wv_  = t >> 6;
    const int lane = t & 63;
    const int mrow = lane & 15;
    const int qk   = lane >> 4;

    f32x4 acc[2][4];
    #pragma unroll
    for (int mt = 0; mt < 2; ++mt)
        #pragma unroll
        for (int nt = 0; nt < 4; ++nt)
            acc[mt][nt] = (f32x4){0.f, 0.f, 0.f, 0.f};

    for (int kc = 0; kc < 4; ++kc) {
        __syncthreads();
        {
            const int n = t;
            #pragma unroll
            for (int k8 = 0; k8 < 64; k8 += 8) {
                bf16x8 v;
                #pragma unroll
                for (int j = 0; j < 8; ++j) {
                    float w = W2[(size_t)(kc * 64 + k8 + j) * H2DIM + n];
                    v[j] = (short)f2bf_rne(w);
                }
                int byte = n * 128 + k8 * 2;
                byte ^= ((n & 7) << 4);
                *(bf16x8*)(w2b + byte) = v;
            }
        }
        __syncthreads();
        #pragma unroll
        for (int ks = 0; ks < 2; ++ks) {
            const int klocal = ks * 32;
            const int kglob  = kc * 64 + klocal;
            bf16x8 afrag[2], bfrag[4];
            #pragma unroll
            for (int mt = 0; mt < 2; ++mt) {
                const int rowi = mt * 16 + mrow;
                int byte = rowi * 512 + (kglob + 8 * qk) * 2;
                byte ^= ((rowi & 7) << 4);
                afrag[mt] = *(const bf16x8*)(h1b + byte);
            }
            #pragma unroll
            for (int nt = 0; nt < 4; ++nt) {
                const int col = wv_ * 64 + nt * 16 + mrow;
                int byte = col * 128 + (klocal + 8 * qk) * 2;
                byte ^= ((col & 7) << 4);
                bfrag[nt] = *(const bf16x8*)(w2b + byte);
            }
            #pragma unroll
            for (int mt = 0; mt < 2; ++mt)
                #pragma unroll
                for (int nt = 0; nt < 4; ++nt)
                    acc[mt][nt] = __builtin_amdgcn_mfma_f32_16x16x32_bf16(
                        afrag[mt], bfrag[nt], acc[mt][nt], 0, 0, 0);
        }
    }

    // ---- epilogue: +b2, leaky, layer-3 partials, reduce ----
    float b2n[4];
    #pragma unroll
    for (int nt = 0; nt < 4; ++nt) b2n[nt] = b2[wv_ * 64 + nt * 16 + mrow];

    float p[8][2];
    #pragma unroll
    for (int i = 0; i < 8; ++i) { p[i][0] = 0.f; p[i][1] = 0.f; }
    #pragma unroll
    for (int mt = 0; mt < 2; ++mt)
        #pragma unroll
        for (int nt = 0; nt < 4; ++nt) {
            const int n = wv_ * 64 + nt * 16 + mrow;
            #pragma unroll
            for (int reg = 0; reg < 4; ++reg) {
                float h2v = leaky02(acc[mt][nt][reg] + b2n[nt]);
                p[mt*4 + reg][0] = fmaf(h2v, wfs[2*n + 0], p[mt*4 + reg][0]);
                p[mt*4 + reg][1] = fmaf(h2v, wfs[2*n + 1], p[mt*4 + reg][1]);
            }
        }
    #pragma unroll
    for (int o = 1; o < 16; o <<= 1) {
        #pragma unroll
        for (int i = 0; i < 8; ++i) {
            p[i][0] += __shfl_xor(p[i][0], o, 64);
            p[i][1] += __shfl_xor(p[i][1], o, 64);
        }
    }
    if (mrow == 0) {
        #pragma unroll
        for (int mt = 0; mt < 2; ++mt)
            #pragma unroll
            for (int reg = 0; reg < 4; ++reg) {
                const int sample = mt * 16 + qk * 4 + reg;   // C row mapping (m89)
                oacc[wv_][sample][0] = p[mt*4 + reg][0];
                oacc[wv_][sample][1] = p[mt*4 + reg][1];
            }
    }
    __syncthreads();
    if (t < 32) {
        float o0 = bf[0], o1 = bf[1];
        #pragma unroll
        for (int w = 0; w < 4; ++w) { o0 += oacc[w][t][0]; o1 += oacc[w][t][1]; }
        float4 o4;
        o4.x = o0; o4.y = o1; o4.z = lstd[0]; o4.w = lstd[1];
        *(float4*)&out[(size_t)(blk * 32 + t) * 4] = o4;
    }
}

extern "C" void kernel_launch(void* const* d_in, const int* in_sizes, int n_in,
                              void* d_out, int out_size, void* d_ws, size_t ws_size,
                              hipStream_t stream) {
    const float* obs   = (const float*)d_in[0];
    const float* Wq    = (const float*)d_in[1];
    const float* bq    = (const float*)d_in[2];
    const float* Wk    = (const float*)d_in[3];
    const float* bk    = (const float*)d_in[4];
    const float* Wv    = (const float*)d_in[5];
    const float* bv    = (const float*)d_in[6];
    const float* v_att = (const float*)d_in[7];
    const float* temp  = (const float*)d_in[8];
    const float* ln_g  = (const float*)d_in[9];
    const float* ln_b  = (const float*)d_in[10];
    const float* W1    = (const float*)d_in[11];
    const float* b1    = (const float*)d_in[12];
    const float* W2    = (const float*)d_in[13];
    const float* b2    = (const float*)d_in[14];
    const float* Wf    = (const float*)d_in[15];
    const float* bf    = (const float*)d_in[16];
    const float* lstd  = (const float*)d_in[17];

    float* xbuf = (float*)d_ws;   // B x 22 normalized features (2.88 MB)
    float* outf = (float*)d_out;

    attn_ln_kernel<<<NBATCH / 16, 256, 0, stream>>>(
        obs, Wq, bq, Wk, bk, Wv, bv, v_att, temp, ln_g, ln_b, xbuf);
    mlp_kernel<<<NBATCH / 32, 256, 0, stream>>>(
        xbuf, W1, b1, W2, b2, Wf, bf, lstd, outf);
}